// Round 19
// baseline (54.178 us; speedup 1.0000x reference)
//
#include <hip/hip_runtime.h>

// CARAFE naive upsample: N=2, C=256, H=100, W=100, K=5, G=1, S=2.
// out[n,c,2h+a,2w+b] = sum_{dy,dx} mask[n,dy*5+dx,2h+a,2w+b] * feat[n,c,h+dy-2,w+dx-2]
//
// Journal: R8=38.1 anchor; R13=37.1 best. Exonerated: occupancy (R11),
// mask latency (R14/R17), VMEM instr count (R15), mask re-read count (R18).
// Unexplained: FETCH=42MB vs 28.5MB total inputs (all L3-fit) -> our own
// 82MB output stream write-allocates in L2/L3 and evicts the input working
// set (R16: longer blocks -> FETCH 68MB confirms). R14's nt stores attacked
// this correctly but TW=25 tiles gave 200B runs -> partial 64B lines ->
// WRITE amplified 80->105MB.
// R19: R8 structure, tile 16x16 (1 px/thread, 256 threads, no dead lanes):
//   per (c,row) store run = 16 lanes x 8B = 128B, 64B-aligned (x0*8=128*tx)
//   -> every line fully covered by one instruction -> nt emits full lines.
//   Instruments: WRITE 80-84MB (nt ok), FETCH ~30MB (pollution gone).

typedef float v2f __attribute__((ext_vector_type(2)));

#define N_ 2
#define C_ 256
#define H_ 100
#define W_ 100
#define CC 8
#define HW_ (H_ * W_)
#define OW_ (W_ * 2)
#define OHW_ (HW_ * 4)
#define NCHUNK (C_ / CC)          // 32
#define TS 16                     // tile side (pixels)
#define HS 20                     // halo side (TS+4)
#define NROW 40                   // HS rows x 2 channel-quads
#define RSTR 21                   // f4 row stride (odd, >= HS)
#define NT7 7                     // tiles per side: 7*16 = 112 >= 100
#define TILES (NT7 * NT7)         // 49

__global__ __launch_bounds__(256) void carafe_kernel(
    const float* __restrict__ feat,
    const float* __restrict__ mask,
    float* __restrict__ out) {

    // row p = y*2 + cq; f4 index p*RSTR + col, innermost c%4.
    __shared__ float4 lds4[NROW * RSTR];   // 40*21*16 = 13,440 B

    const int cchunk = blockIdx.x;         // chunk-fastest (R8 L3 locality)
    const int tile   = blockIdx.y;
    const int n      = blockIdx.z;
    const int tx = tile % NT7;
    const int ty = tile / NT7;
    const int x0 = tx * TS;
    const int y0 = ty * TS;
    const int t = threadIdx.x;

    // ---- stage features channels-last (R8 pattern; 800 items) ----
    {
        const float* fb = feat + (n * C_ + cchunk * CC) * HW_;
#pragma unroll
        for (int r = 0; r < 4; ++r) {
            const int i = r * 256 + t;     // 0..1023, active < 800
            if (i < NROW * HS) {
                const int row = i / HS;    // 0..39
                const int col = i % HS;    // 0..19
                const int y  = row >> 1;
                const int cq = row & 1;
                const int yy = y0 - 2 + y;
                const int xx = x0 - 2 + col;
                float4 v = make_float4(0.f, 0.f, 0.f, 0.f);
                if (((unsigned)yy < (unsigned)H_) & ((unsigned)xx < (unsigned)W_)) {
                    const int o = (cq * 4) * HW_ + yy * W_ + xx;
                    v.x = fb[o];
                    v.y = fb[o + HW_];
                    v.z = fb[o + 2 * HW_];
                    v.w = fb[o + 3 * HW_];
                }
                lds4[row * RSTR + col] = v;
            }
        }
    }
    __syncthreads();

    // ---- compute: 1 pixel per thread, all 256 threads ----
    const int py = t >> 4;                 // 0..15
    const int wl = t & 15;                 // 0..15
    const int h = y0 + py;
    const int w = x0 + wl;
    const bool alive = (h < H_) & (w < W_);
    const int hc = min(h, H_ - 1), wc = min(w, W_ - 1);  // clamp dead lanes
    const int oh0 = 2 * hc;
    const int ow0 = 2 * wc;
    const float* mbase = mask + n * (25 * OHW_) + oh0 * OW_ + ow0;

    v2f a0[CC], a1[CC];
#pragma unroll
    for (int c = 0; c < CC; ++c) { a0[c] = (v2f){0.f, 0.f}; a1[c] = (v2f){0.f, 0.f}; }

#pragma unroll 2
    for (int dy = 0; dy < 5; ++dy) {
        const int ry = (py + dy) * 2;
        const float* mrow = mbase + (dy * 5) * OHW_;
#pragma unroll
        for (int dx = 0; dx < 5; ++dx) {
            const v2f m0 = *reinterpret_cast<const v2f*>(mrow + dx * OHW_);        // a=0
            const v2f m1 = *reinterpret_cast<const v2f*>(mrow + dx * OHW_ + OW_);  // a=1
            const float4 lo = lds4[ry * RSTR + wl + dx];        // c0..3
            const float4 hi = lds4[(ry + 1) * RSTR + wl + dx];  // c4..7
            const float f[8] = {lo.x, lo.y, lo.z, lo.w, hi.x, hi.y, hi.z, hi.w};
#pragma unroll
            for (int c = 0; c < CC; ++c) {
                const v2f fv = {f[c], f[c]};
                a0[c] = __builtin_elementwise_fma(fv, m0, a0[c]);   // v_pk_fma_f32
                a1[c] = __builtin_elementwise_fma(fv, m1, a1[c]);
            }
        }
    }

    // ---- full-line nontemporal stores: 16 lanes x 8B = 128B aligned runs ----
    if (alive) {
        float* ob = out + (n * C_ + cchunk * CC) * OHW_ + oh0 * OW_ + ow0;
#pragma unroll
        for (int c = 0; c < CC; ++c) {
            __builtin_nontemporal_store(a0[c], reinterpret_cast<v2f*>(ob + c * OHW_));
            __builtin_nontemporal_store(a1[c], reinterpret_cast<v2f*>(ob + c * OHW_ + OW_));
        }
    }
}

extern "C" void kernel_launch(void* const* d_in, const int* in_sizes, int n_in,
                              void* d_out, int out_size, void* d_ws, size_t ws_size,
                              hipStream_t stream) {
    const float* feat = (const float*)d_in[0];
    const float* mask = (const float*)d_in[1];
    float* out = (float*)d_out;

    dim3 grid(NCHUNK, TILES, N_);   // 32 x 49 x 2 = 3136 blocks
    carafe_kernel<<<grid, 256, 0, stream>>>(feat, mask, out);
}

// Round 20
// 38.578 us; speedup vs baseline: 1.4044x; 1.4044x over previous
//
#include <hip/hip_runtime.h>

// CARAFE naive upsample: N=2, C=256, H=100, W=100, K=5, G=1, S=2.
// out[n,c,2h+a,2w+b] = sum_{dy,dx} mask[n,dy*5+dx,2h+a,2w+b] * feat[n,c,h+dy-2,w+dx-2]
//
// Journal: R13=37.1 best. Exonerated: occupancy(R11), mask latency(R14/R17),
// mask re-reads(R18), nt-stores(R14/R19 both WRITE-amplified -> closed).
// Moves time: VMEM/LDS instr counts + bank conflicts. R15 (VMEM 82->49) gave
// back ~6us in conflicts (even-stride reads, 4.15M); R9's phys_x=x+(x>>1)
// swizzle fixed that class (1.79M) but halved wave count. R20 combines them:
//   - tile 16x16, threads=(hl:16, a:2, wp:8)=256 exact, zero dead lanes
//   - masks: 25 lane-dense f4 loads (8 lanes x 16B = 128B runs)
//   - features: channels-last LDS, phys_x = x+(x>>1), RSTR=29; read base
//     3wp+j+(j>>1): 3wp%8 covers all 8 bank-groups -> conflict-free
//   - stores: 8 plain f4 (no nt). VMEM 49/thread total.

typedef float v4f __attribute__((ext_vector_type(4)));

#define N_ 2
#define C_ 256
#define H_ 100
#define W_ 100
#define CC 8
#define HW_ (H_ * W_)
#define OW_ (W_ * 2)
#define OHW_ (HW_ * 4)
#define NCHUNK (C_ / CC)          // 32
#define TS 16                     // tile side (pixels)
#define HS 20                     // halo side (TS+4)
#define NROW 40                   // HS rows x 2 channel-quads
#define RSTR 29                   // phys f4 row stride (odd; phys(19)=28)
#define NT7 7                     // 7*16 = 112 >= 100
#define TILES (NT7 * NT7)         // 49

__global__ __launch_bounds__(256) void carafe_kernel(
    const float* __restrict__ feat,
    const float* __restrict__ mask,
    float* __restrict__ out) {

    // row = y*2 + cq; f4 index row*RSTR + col + (col>>1)  (phys-x swizzle)
    __shared__ v4f lds4[NROW * RSTR];      // 40*29*16 = 18,560 B

    const int cchunk = blockIdx.x;         // chunk-fastest (R8 locality)
    const int tile   = blockIdx.y;
    const int n      = blockIdx.z;
    const int tx = tile % NT7;
    const int ty = tile / NT7;
    const int x0 = tx * TS;
    const int y0 = ty * TS;
    const int t = threadIdx.x;

    // ---- stage features channels-last with phys-x swizzle (800 items) ----
    {
        const float* fb = feat + (n * C_ + cchunk * CC) * HW_;
#pragma unroll
        for (int r = 0; r < 4; ++r) {
            const int i = r * 256 + t;     // active < 800
            if (i < NROW * HS) {
                const int row = i / HS;    // 0..39
                const int col = i % HS;    // 0..19
                const int y  = row >> 1;
                const int cq = row & 1;
                const int yy = y0 - 2 + y;
                const int xx = x0 - 2 + col;
                v4f v = {0.f, 0.f, 0.f, 0.f};
                if (((unsigned)yy < (unsigned)H_) & ((unsigned)xx < (unsigned)W_)) {
                    const int o = (cq * 4) * HW_ + yy * W_ + xx;
                    v.x = fb[o];
                    v.y = fb[o + HW_];
                    v.z = fb[o + 2 * HW_];
                    v.w = fb[o + 3 * HW_];
                }
                lds4[row * RSTR + col + (col >> 1)] = v;
            }
        }
    }
    __syncthreads();

    // ---- compute: thread = (hl, a, wp) -> one output row x 4 cols x 8 ch ----
    const int hl  = t >> 4;                // 0..15
    const int rem = t & 15;
    const int a   = rem >> 3;              // 0..1
    const int wp  = rem & 7;               // 0..7

    const int h     = y0 + hl;
    const int xpair = x0 + 2 * wp;         // even
    const bool alive = (h < H_) & (xpair < W_);   // W_ even -> pair all-or-none
    const int hc   = min(h, H_ - 1);
    const int xpc  = min(xpair, W_ - 2);
    const int oh   = 2 * hc + a;
    const int ow0  = 2 * xpc;              // multiple of 4 -> f4 aligned
    const float* mbase = mask + n * (25 * OHW_) + oh * OW_ + ow0;

    v4f acc[CC];                           // [c] = cols ow0..ow0+3
#pragma unroll
    for (int c = 0; c < CC; ++c) acc[c] = (v4f){0.f, 0.f, 0.f, 0.f};

    const int b3 = 3 * wp;                 // phys(2wp + j) = 3wp + j + (j>>1)

#pragma unroll 2
    for (int dy = 0; dy < 5; ++dy) {
        const int p0 = ((hl + dy) * 2) * RSTR + b3;   // quad 0 row base
        const int p1 = p0 + RSTR;                      // quad 1

        // one lane-dense f4 mask load per tap
        v4f m[5];
#pragma unroll
        for (int dx = 0; dx < 5; ++dx)
            m[dx] = *reinterpret_cast<const v4f*>(mbase + (dy * 5 + dx) * OHW_);

        // 12 b128 reads serve both pixels' 5-tap windows (swizzled offsets)
        v4f f0[6], f1[6];
#pragma unroll
        for (int j = 0; j < 6; ++j) {
            const int off = j + (j >> 1);  // 0,1,3,4,6,7
            f0[j] = lds4[p0 + off];        // c0..3
            f1[j] = lds4[p1 + off];        // c4..7
        }

#pragma unroll
        for (int dx = 0; dx < 5; ++dx) {
#pragma unroll
            for (int c = 0; c < CC; ++c) {
                const float fl = (c < 4) ? f0[dx][c]     : f1[dx][c - 4];     // pixel 0
                const float fr = (c < 4) ? f0[dx + 1][c] : f1[dx + 1][c - 4]; // pixel 1
                const v4f fv = {fl, fl, fr, fr};
                acc[c] = __builtin_elementwise_fma(fv, m[dx], acc[c]);  // 2x v_pk_fma
            }
        }
    }

    if (alive) {
        float* ob = out + (n * C_ + cchunk * CC) * OHW_ + oh * OW_ + ow0;
#pragma unroll
        for (int c = 0; c < CC; ++c)
            *reinterpret_cast<v4f*>(ob + c * OHW_) = acc[c];
    }
}

extern "C" void kernel_launch(void* const* d_in, const int* in_sizes, int n_in,
                              void* d_out, int out_size, void* d_ws, size_t ws_size,
                              hipStream_t stream) {
    const float* feat = (const float*)d_in[0];
    const float* mask = (const float*)d_in[1];
    float* out = (float*)d_out;

    dim3 grid(NCHUNK, TILES, N_);   // 32 x 49 x 2 = 3136 blocks
    carafe_kernel<<<grid, 256, 0, stream>>>(feat, mask, out);
}